// Round 4
// baseline (672.530 us; speedup 1.0000x reference)
//
#include <hip/hip_runtime.h>
#include <stdint.h>
#include <math.h>

typedef float f32x4 __attribute__((ext_vector_type(4)));
typedef __bf16 bf16x8 __attribute__((ext_vector_type(8)));
typedef unsigned int u32x4 __attribute__((ext_vector_type(4)));
typedef unsigned short u16;

#define DEVINL static __device__ __forceinline__

DEVINL u16 f2bf(float f) {
  union { float f; unsigned u; } x; x.f = f;
  unsigned r = x.u + 0x7fffu + ((x.u >> 16) & 1u);
  return (u16)(r >> 16);
}

DEVINL void gload_lds16(const void* g, void* l) {
  __builtin_amdgcn_global_load_lds(
      (__attribute__((address_space(1))) void*)(g),
      (__attribute__((address_space(3))) void*)(l), 16, 0, 0);
}

// ---------------- cast f32 -> bf16 ----------------
__global__ void cast_kernel(const float* __restrict__ src, u16* __restrict__ dst, int n) {
  int i = (blockIdx.x * 256 + threadIdx.x) * 4;
  if (i >= n) return;
  float4 v = *(const float4*)(src + i);
  u16 o[4] = { f2bf(v.x), f2bf(v.y), f2bf(v.z), f2bf(v.w) };
  *(uint64_t*)(dst + i) = *(uint64_t*)o;
}

// ---------------- NT GEMM: C[M,N] = A[M,K] @ B[N,K]^T, 128x128 tile ----------------
template<int EPI>
__global__ __launch_bounds__(256, 2) void gemm_nt(
    const u16* __restrict__ A, int lda, const u16* __restrict__ B, int ldb,
    void* __restrict__ C, int ldc, int coff,
    const float* __restrict__ bias, const float* __restrict__ alpha,
    int N128, int K, float scale)
{
  __shared__ __align__(16) u16 at[2][128 * 64];
  __shared__ __align__(16) u16 bt[2][128 * 64];
  const int tid = threadIdx.x;
  const int w = tid >> 6, lane = tid & 63, r = lane & 15, kg = lane >> 4;
  const int bm = blockIdx.x / N128, bn = blockIdx.x % N128;
  const int m0 = bm * 128, n0 = bn * 128;

  f32x4 acc[4][4];
  #pragma unroll
  for (int m = 0; m < 4; ++m)
    #pragma unroll
    for (int n = 0; n < 4; ++n) acc[m][n] = f32x4{0.f, 0.f, 0.f, 0.f};

  const int srow = tid >> 3, sc = tid & 7;
  const int nk = K >> 6;

  #pragma unroll
  for (int i = 0; i < 4; ++i) {
    int row = srow + i * 32, cs = (sc ^ row) & 7;
    gload_lds16(A + (size_t)(m0 + row) * lda + cs * 8, at[0] + i * 2048 + w * 512);
    gload_lds16(B + (size_t)(n0 + row) * ldb + cs * 8, bt[0] + i * 2048 + w * 512);
  }
  __syncthreads();

  for (int kt = 0; kt < nk; ++kt) {
    const int cur = kt & 1;
    if (kt + 1 < nk) {
      #pragma unroll
      for (int i = 0; i < 4; ++i) {
        int row = srow + i * 32, cs = (sc ^ row) & 7;
        int kcol = (kt + 1) * 64 + cs * 8;
        gload_lds16(A + (size_t)(m0 + row) * lda + kcol, at[cur ^ 1] + i * 2048 + w * 512);
        gload_lds16(B + (size_t)(n0 + row) * ldb + kcol, bt[cur ^ 1] + i * 2048 + w * 512);
      }
    }
    #pragma unroll
    for (int ks = 0; ks < 2; ++ks) {
      bf16x8 af[4], bff[4];
      #pragma unroll
      for (int m = 0; m < 4; ++m) {
        int row = (w >> 1) * 64 + m * 16 + r;
        int cs = ((ks * 4 + kg) ^ row) & 7;
        af[m] = *(const bf16x8*)(at[cur] + row * 64 + cs * 8);
      }
      #pragma unroll
      for (int n = 0; n < 4; ++n) {
        int row = (w & 1) * 64 + n * 16 + r;
        int cs = ((ks * 4 + kg) ^ row) & 7;
        bff[n] = *(const bf16x8*)(bt[cur] + row * 64 + cs * 8);
      }
      #pragma unroll
      for (int m = 0; m < 4; ++m)
        #pragma unroll
        for (int n = 0; n < 4; ++n)
          acc[m][n] = __builtin_amdgcn_mfma_f32_16x16x32_bf16(af[m], bff[n], acc[m][n], 0, 0, 0);
    }
    __syncthreads();
  }

  #pragma unroll
  for (int m = 0; m < 4; ++m) {
    #pragma unroll
    for (int n = 0; n < 4; ++n) {
      const int gcol = n0 + (w & 1) * 64 + n * 16 + r;
      #pragma unroll
      for (int reg = 0; reg < 4; ++reg) {
        const int grow = m0 + (w >> 1) * 64 + m * 16 + kg * 4 + reg;
        float v = acc[m][n][reg];
        if (EPI == 1) v += bias[grow]; else v += bias[gcol];
        if (EPI == 0) v *= scale;
        if (EPI == 2) v = 0.5f * v * (1.f + erff(v * 0.70710678118654752f));
        if (EPI == 3) {
          float a = alpha[gcol];
          v = (v >= 0.f) ? v : a * v;
          ((float*)C)[(size_t)grow * ldc + coff + gcol] = v;
        } else {
          ((u16*)C)[(size_t)grow * ldc + coff + gcol] = f2bf(v);
        }
      }
    }
  }
}

// ---------------- flash attention: reg-staged 9-phase ring pipeline ----------------
// Chunk stream per j: c = [K0,K1,K2,K3, D, V0,V1,V2,V3], each 16KB. Ring slot of
// chunk c = (j + c) & 3. Phase p (0..8):
//   [barrier passed]
//   ds_write ring[(j+p+1)&3] <- R   (chunk p+1; compiler inserts counted vmcnt)
//   issue global loads -> R         (chunk p+2; plain loads, precise reg tracking)
//   compute chunk p                 (16 MFMA / softmax phase)
//   s_waitcnt lgkmcnt(0); s_barrier (writes visible to all waves)
// No global_load_lds => no LDS-DMA alias drains (R1/R2 failure mode).
__global__ __launch_bounds__(256, 2) void flash_kernel(
    const u16* __restrict__ Qb, const u16* __restrict__ Kb,
    const u16* __restrict__ VTb, const float* __restrict__ Dm,
    float* __restrict__ Op, float* __restrict__ lp)
{
  __shared__ __align__(16) u16 ring[4][8192];   // 4 x 16KB
  __shared__ __align__(16) u16 pbuf[4][16 * 64]; // per-wave P, swizzled
  const int tid = threadIdx.x;
  const int w = tid >> 6, lane = tid & 63, r = lane & 15, kg = lane >> 4;
  const int s = blockIdx.x & 3, qb = blockIdx.x >> 2;
  const int q0 = qb * 64;
  const int kvb = s * 2048;

  const int rK = tid >> 4, cK = tid & 15;  // K/D shape: rows of 256B, 16 granules
  const int rV = tid >> 3, cV = tid & 7;   // V shape:   rows of 128B, 8 granules

  u32x4 R[4];

  auto loadK = [&](int jj, int kc) {
    const u16* src = Kb + (size_t)(kvb + jj * 64) * 512 + kc * 128 + cK * 8;
    #pragma unroll
    for (int i = 0; i < 4; ++i)
      R[i] = *(const u32x4*)(src + (size_t)(rK + i * 16) * 512);
  };
  auto loadD = [&](int jj) {
    const float* src = Dm + (size_t)q0 * 8192 + kvb + jj * 64 + cK * 4;
    #pragma unroll
    for (int i = 0; i < 4; ++i)
      R[i] = __builtin_nontemporal_load(
          (const u32x4*)(src + (size_t)(rK + i * 16) * 8192));
  };
  auto loadV = [&](int jj, int dc) {
    const u16* src = VTb + (size_t)dc * 128 * 8192 + kvb + jj * 64 + cV * 8;
    #pragma unroll
    for (int i = 0; i < 4; ++i)
      R[i] = *(const u32x4*)(src + (size_t)(rV + i * 32) * 8192);
  };
  auto writeK = [&](int slot) {  // also used for D (same 256B-row shape)
    #pragma unroll
    for (int i = 0; i < 4; ++i) {
      const int row = rK + i * 16;
      const int cs = (cK & 8) | ((cK ^ row) & 7);
      *(u32x4*)(ring[slot] + row * 128 + cs * 8) = R[i];
    }
  };
  auto writeV = [&](int slot) {
    #pragma unroll
    for (int i = 0; i < 4; ++i) {
      const int row = rV + i * 32;
      const int cs = (cV ^ row) & 7;
      *(u32x4*)(ring[slot] + row * 64 + cs * 8) = R[i];
    }
  };

  // Q fragments resident in registers (this wave's 16 q-rows)
  bf16x8 aq[16];
  {
    const u16* qrow = Qb + (size_t)(q0 + w * 16 + r) * 512;
    #pragma unroll
    for (int ks = 0; ks < 16; ++ks) aq[ks] = *(const bf16x8*)(qrow + ks * 32 + kg * 8);
  }

  f32x4 o[32];
  #pragma unroll
  for (int i = 0; i < 32; ++i) o[i] = f32x4{0.f, 0.f, 0.f, 0.f};
  float lsum[4] = {0.f, 0.f, 0.f, 0.f};

  // prologue: chunk0 -> ring, chunk1 -> R
  loadK(0, 0);
  writeK(0);                       // slot (j=0,c=0) = 0
  loadK(0, 1);
  asm volatile("s_waitcnt lgkmcnt(0)" ::: "memory");
  __builtin_amdgcn_s_barrier();

  #pragma unroll 1
  for (int j = 0; j < 32; ++j) {
    f32x4 sacc[4];
    #pragma unroll
    for (int t = 0; t < 4; ++t) sacc[t] = f32x4{0.f, 0.f, 0.f, 0.f};
    bf16x8 ap[2];

    #pragma unroll
    for (int p = 0; p < 9; ++p) {
      // 1. ds_write chunk p+1 (R was loaded last phase; counted vmcnt auto)
      {
        const int c1 = p + 1;  // 1..9 ; 4 = D (K-shape), 9 = K0 of j+1
        const int wslot = (j + p + 1) & 3;
        if (c1 <= 4 || c1 == 9) writeK(wslot);
        else writeV(wslot);
      }
      // 2. issue loads for chunk p+2
      {
        const int c2 = p + 2;  // 2..10
        if (c2 < 4)       loadK(j, c2);
        else if (c2 == 4) loadD(j);
        else if (c2 < 9)  loadV(j, c2 - 5);
        else { const int jj = (j < 31) ? j + 1 : 31; loadK(jj, c2 - 9); }
      }
      const u16* cb = ring[(j + p) & 3];

      // 3. compute chunk p
      if (p < 4) {  // QK^T quarter (k-cols p*128..)
        __builtin_amdgcn_s_setprio(1);
        #pragma unroll
        for (int ks2 = 0; ks2 < 4; ++ks2) {
          const bf16x8 a = aq[p * 4 + ks2];
          #pragma unroll
          for (int t = 0; t < 4; ++t) {
            const int row = t * 16 + r;
            const int c = ks2 * 4 + kg;
            const int cs = (c & 8) | ((c ^ row) & 7);
            const bf16x8 b = *(const bf16x8*)(cb + row * 128 + cs * 8);
            sacc[t] = __builtin_amdgcn_mfma_f32_16x16x32_bf16(a, b, sacc[t], 0, 0, 0);
          }
        }
        __builtin_amdgcn_s_setprio(0);
      } else if (p == 4) {  // softmax: P = exp(D*S) from LDS D chunk
        const char* db = (const char*)cb;
        #pragma unroll
        for (int t = 0; t < 4; ++t) {
          #pragma unroll
          for (int reg = 0; reg < 4; ++reg) {
            const int qr = w * 16 + kg * 4 + reg;     // q-row in block (0..63)
            const int g = t * 4 + (r >> 2);           // kv granule (0..15)
            const int pos = (g & 8) | ((g ^ qr) & 7);
            const float dval = *(const float*)(db + qr * 256 + pos * 16 + (r & 3) * 4);
            const float pv = __expf(sacc[t][reg] * dval);
            lsum[reg] += pv;
            const int prow = kg * 4 + reg, pcol = t * 16 + r;
            const int byt = prow * 128 + (((pcol >> 3) ^ prow) & 7) * 16 + (pcol & 7) * 2;
            *(u16*)((char*)pbuf[w] + byt) = f2bf(pv);
          }
        }
        #pragma unroll
        for (int ks = 0; ks < 2; ++ks) {
          const int cs = ((ks * 4 + kg) ^ r) & 7;
          ap[ks] = *(const bf16x8*)((const char*)pbuf[w] + r * 128 + cs * 16);
        }
      } else {  // PV quarter: d-rows (p-5)*128..
        const int dc = p - 5;
        __builtin_amdgcn_s_setprio(1);
        #pragma unroll
        for (int t2 = 0; t2 < 8; ++t2) {
          const int row = t2 * 16 + r;
          #pragma unroll
          for (int ks = 0; ks < 2; ++ks) {
            const int cs = ((ks * 4 + kg) ^ row) & 7;
            const bf16x8 b = *(const bf16x8*)(cb + row * 64 + cs * 8);
            o[dc * 8 + t2] = __builtin_amdgcn_mfma_f32_16x16x32_bf16(ap[ks], b, o[dc * 8 + t2], 0, 0, 0);
          }
        }
        __builtin_amdgcn_s_setprio(0);
      }

      // 4. make this phase's ds_writes visible, then sync
      asm volatile("s_waitcnt lgkmcnt(0)" ::: "memory");
      __builtin_amdgcn_s_barrier();
    }
  }

  #pragma unroll
  for (int reg = 0; reg < 4; ++reg) {
    float v = lsum[reg];
    v += __shfl_xor(v, 1); v += __shfl_xor(v, 2);
    v += __shfl_xor(v, 4); v += __shfl_xor(v, 8);
    lsum[reg] = v;
  }

  float* ob = Op + (size_t)s * (8192 * 512) + (size_t)(q0 + w * 16 + kg * 4) * 512 + r;
  #pragma unroll
  for (int ti = 0; ti < 32; ++ti)
    #pragma unroll
    for (int reg = 0; reg < 4; ++reg)
      ob[(size_t)reg * 512 + ti * 16] = o[ti][reg];

  if (r == 0) {
    #pragma unroll
    for (int reg = 0; reg < 4; ++reg)
      lp[(size_t)s * 8192 + q0 + w * 16 + kg * 4 + reg] = lsum[reg];
  }
}

// ---------------- combine KV-split partials -> h_ret (bf16) ----------------
__global__ void combine_kernel(const float* __restrict__ Op, const float* __restrict__ lp,
                               u16* __restrict__ hrb) {
  const int idx = (blockIdx.x * 256 + threadIdx.x) * 4;
  const int q = idx >> 9;
  const float li = 1.f / (lp[q] + lp[8192 + q] + lp[16384 + q] + lp[24576 + q]);
  float4 a = *(const float4*)(Op + idx);
  const float4 b = *(const float4*)(Op + 4194304 + idx);
  const float4 c = *(const float4*)(Op + 8388608 + idx);
  const float4 d = *(const float4*)(Op + 12582912 + idx);
  a.x += b.x + c.x + d.x; a.y += b.y + c.y + d.y;
  a.z += b.z + c.z + d.z; a.w += b.w + c.w + d.w;
  u16 o[4] = { f2bf(a.x * li), f2bf(a.y * li), f2bf(a.z * li), f2bf(a.w * li) };
  *(uint64_t*)(hrb + idx) = *(uint64_t*)o;
}

// ---------------- GroupNorm ----------------
__global__ void gn_stats_kernel(const float* __restrict__ x, float* __restrict__ part) {
  const int g = blockIdx.x >> 4, ch = blockIdx.x & 15;
  const int t = threadIdx.x;
  float s = 0.f, ss = 0.f;
  const int cl = (t & 7) * 4;
  const int r0 = ch * 512 + (t >> 3);
  for (int i = 0; i < 16; ++i) {
    const float4 v = *(const float4*)(x + (size_t)(r0 + i * 32) * 512 + g * 32 + cl);
    s += v.x + v.y + v.z + v.w;
    ss += v.x * v.x + v.y * v.y + v.z * v.z + v.w * v.w;
  }
  #pragma unroll
  for (int m = 1; m < 64; m <<= 1) { s += __shfl_xor(s, m); ss += __shfl_xor(ss, m); }
  __shared__ float red[8];
  const int w = t >> 6, lane = t & 63;
  if (lane == 0) { red[w * 2] = s; red[w * 2 + 1] = ss; }
  __syncthreads();
  if (t == 0) {
    part[blockIdx.x * 2]     = red[0] + red[2] + red[4] + red[6];
    part[blockIdx.x * 2 + 1] = red[1] + red[3] + red[5] + red[7];
  }
}

__global__ void gn_finalize_kernel(const float* __restrict__ part, float* __restrict__ mv) {
  const int g = threadIdx.x;
  if (g < 16) {
    float s = 0.f, ss = 0.f;
    for (int ch = 0; ch < 16; ++ch) {
      s  += part[(g * 16 + ch) * 2];
      ss += part[(g * 16 + ch) * 2 + 1];
    }
    const float mean = s * (1.f / 262144.f);
    const float var = ss * (1.f / 262144.f) - mean * mean;
    mv[g * 2] = mean;
    mv[g * 2 + 1] = rsqrtf(var + 1e-5f);
  }
}

__global__ void gn_norm_kernel(const float* __restrict__ x, const float* __restrict__ mv,
                               const float* __restrict__ gamma, const float* __restrict__ beta,
                               float* __restrict__ out) {
  const int idx = (blockIdx.x * 256 + threadIdx.x) * 4;
  const int c = idx & 511, g = c >> 5;
  const float mean = mv[g * 2], rs = mv[g * 2 + 1];
  float4 v = *(const float4*)(x + idx);
  const float4 gm = *(const float4*)(gamma + c);
  const float4 bt = *(const float4*)(beta + c);
  v.x = (v.x - mean) * rs * gm.x + bt.x;
  v.y = (v.y - mean) * rs * gm.y + bt.y;
  v.z = (v.z - mean) * rs * gm.z + bt.z;
  v.w = (v.w - mean) * rs * gm.w + bt.w;
  *(float4*)(out + idx) = v;
}

// ---------------- launch ----------------
extern "C" void kernel_launch(void* const* d_in, const int* in_sizes, int n_in,
                              void* d_out, int out_size, void* d_ws, size_t ws_size,
                              hipStream_t stream) {
  (void)in_sizes; (void)n_in; (void)out_size; (void)ws_size;
  const float* h     = (const float*)d_in[0];
  const float* Dm    = (const float*)d_in[1];
  const float* hp    = (const float*)d_in[2];
  const float* Wq    = (const float*)d_in[3];
  const float* bq    = (const float*)d_in[4];
  const float* Wk    = (const float*)d_in[5];
  const float* bk    = (const float*)d_in[6];
  const float* Wv    = (const float*)d_in[7];
  const float* bv    = (const float*)d_in[8];
  const float* Wr    = (const float*)d_in[9];
  const float* br    = (const float*)d_in[10];
  const float* Wc    = (const float*)d_in[11];
  const float* bc    = (const float*)d_in[12];
  const float* Wp    = (const float*)d_in[13];
  const float* bp    = (const float*)d_in[14];
  const float* alpha = (const float*)d_in[15];
  const float* gamma = (const float*)d_in[16];
  const float* beta  = (const float*)d_in[17];

  char* ws = (char*)d_ws;
  u16*   hb   = (u16*)(ws + 0);
  u16*   hpb  = (u16*)(ws + 8388608);
  u16*   Qb   = (u16*)(ws + 16777216);
  u16*   Kb   = (u16*)(ws + 25165824);
  u16*   VTb  = (u16*)(ws + 33554432);
  u16*   hrb  = (u16*)(ws + 41943040);
  u16*   Wqb  = (u16*)(ws + 50331648);
  u16*   Wkb  = (u16*)(ws + 50855936);
  u16*   Wvb  = (u16*)(ws + 51380224);
  u16*   Wrb  = (u16*)(ws + 51904512);
  u16*   Wcb  = (u16*)(ws + 52953088);
  u16*   Wpb  = (u16*)(ws + 54001664);
  u16*   xcat = (u16*)(ws + 56098816);
  float* xf   = (float*)(ws + 89653248);
  float* Op   = (float*)(ws + 106430464);
  float* lp   = (float*)(ws + 173539328);
  float* gp   = (float*)(ws + 173670400);
  float* mv   = (float*)(ws + 173672448);

  cast_kernel<<<4096, 256, 0, stream>>>(h, hb, 4194304);
  cast_kernel<<<4096, 256, 0, stream>>>(hp, hpb, 4194304);
  cast_kernel<<<256, 256, 0, stream>>>(Wq, Wqb, 262144);
  cast_kernel<<<256, 256, 0, stream>>>(Wk, Wkb, 262144);
  cast_kernel<<<256, 256, 0, stream>>>(Wv, Wvb, 262144);
  cast_kernel<<<512, 256, 0, stream>>>(Wr, Wrb, 524288);
  cast_kernel<<<512, 256, 0, stream>>>(Wc, Wcb, 524288);
  cast_kernel<<<1024, 256, 0, stream>>>(Wp, Wpb, 1048576);

  // Q = (h Wq^T + bq)/sqrt(512) ; K = h Wk^T + bk ; V^T = Wv h^T + bv (row bias)
  gemm_nt<0><<<256, 256, 0, stream>>>(hb, 512, Wqb, 512, Qb, 512, 0, bq, nullptr, 4, 512, 0.044194173824159216f);
  gemm_nt<0><<<256, 256, 0, stream>>>(hb, 512, Wkb, 512, Kb, 512, 0, bk, nullptr, 4, 512, 1.0f);
  gemm_nt<1><<<256, 256, 0, stream>>>(Wvb, 512, hb, 512, VTb, 8192, 0, bv, nullptr, 64, 512, 1.0f);

  flash_kernel<<<512, 256, 0, stream>>>(Qb, Kb, VTb, Dm, Op, lp);
  combine_kernel<<<4096, 256, 0, stream>>>(Op, lp, hrb);

  // xcat[:, :1024] = gelu(h_ret Wr^T + br) ; xcat[:, 1024:] = h' Wc^T + bc
  gemm_nt<2><<<512, 256, 0, stream>>>(hrb, 512, Wrb, 512, xcat, 2048, 0, br, nullptr, 8, 512, 1.0f);
  gemm_nt<0><<<512, 256, 0, stream>>>(hpb, 512, Wcb, 512, xcat, 2048, 1024, bc, nullptr, 8, 512, 1.0f);
  // x = prelu(xcat Wp^T + bp) (f32)
  gemm_nt<3><<<256, 256, 0, stream>>>(xcat, 2048, Wpb, 2048, xf, 512, 0, bp, alpha, 4, 2048, 1.0f);

  gn_stats_kernel<<<256, 256, 0, stream>>>(xf, gp);
  gn_finalize_kernel<<<1, 64, 0, stream>>>(gp, mv);
  gn_norm_kernel<<<4096, 256, 0, stream>>>(xf, mv, gamma, beta, (float*)d_out);
}

// Round 5
// 462.808 us; speedup vs baseline: 1.4532x; 1.4532x over previous
//
#include <hip/hip_runtime.h>
#include <stdint.h>
#include <math.h>

typedef float f32x4 __attribute__((ext_vector_type(4)));
typedef __bf16 bf16x8 __attribute__((ext_vector_type(8)));
typedef unsigned int u32x4 __attribute__((ext_vector_type(4)));
typedef unsigned short u16;

#define DEVINL static __device__ __forceinline__

DEVINL u16 f2bf(float f) {
  union { float f; unsigned u; } x; x.f = f;
  unsigned r = x.u + 0x7fffu + ((x.u >> 16) & 1u);
  return (u16)(r >> 16);
}

DEVINL void gload_lds16(const void* g, void* l) {
  __builtin_amdgcn_global_load_lds(
      (__attribute__((address_space(1))) void*)(g),
      (__attribute__((address_space(3))) void*)(l), 16, 0, 0);
}

// ---------------- cast f32 -> bf16 ----------------
__global__ void cast_kernel(const float* __restrict__ src, u16* __restrict__ dst, int n) {
  int i = (blockIdx.x * 256 + threadIdx.x) * 4;
  if (i >= n) return;
  float4 v = *(const float4*)(src + i);
  u16 o[4] = { f2bf(v.x), f2bf(v.y), f2bf(v.z), f2bf(v.w) };
  *(uint64_t*)(dst + i) = *(uint64_t*)o;
}

// ---------------- NT GEMM: C[M,N] = A[M,K] @ B[N,K]^T, 128x128 tile ----------------
// EPI: 0 = (acc+bias[col])*scale -> bf16 ; 1 = acc+bias[row] -> bf16 (V^T)
//      2 = gelu(acc+bias[col]) -> bf16   ; 3 = prelu(acc+bias[col], alpha[col]) -> f32
//      4 = acc*scale -> bf16 (no bias)   ; 5 = acc / bias[row] -> bf16 (PV normalize)
// map: 0 = linear (bm=bid/N128); 1 = PV XCD-grouped (grid 256, N128=4);
//      2 = S-GEMM XCD-chunked (grid 4096, N128=64)
template<int EPI>
__global__ __launch_bounds__(256, 2) void gemm_nt(
    const u16* __restrict__ A, int lda, const u16* __restrict__ B, int ldb,
    void* __restrict__ C, int ldc, int coff,
    const float* __restrict__ bias, const float* __restrict__ alpha,
    int N128, int K, float scale, int map)
{
  __shared__ __align__(16) u16 at[2][128 * 64];
  __shared__ __align__(16) u16 bt[2][128 * 64];
  const int tid = threadIdx.x;
  const int w = tid >> 6, lane = tid & 63, r = lane & 15, kg = lane >> 4;
  int bm, bn;
  if (map == 1)      { const int x = blockIdx.x & 7, i = blockIdx.x >> 3; bm = x * 8 + (i >> 2); bn = i & 3; }
  else if (map == 2) { const int x = blockIdx.x & 7, i = blockIdx.x >> 3; bm = x * 8 + (i >> 6); bn = i & 63; }
  else               { bm = blockIdx.x / N128; bn = blockIdx.x % N128; }
  const int m0 = bm * 128, n0 = bn * 128;

  f32x4 acc[4][4];
  #pragma unroll
  for (int m = 0; m < 4; ++m)
    #pragma unroll
    for (int n = 0; n < 4; ++n) acc[m][n] = f32x4{0.f, 0.f, 0.f, 0.f};

  const int srow = tid >> 3, sc = tid & 7;
  const int nk = K >> 6;

  #pragma unroll
  for (int i = 0; i < 4; ++i) {
    int row = srow + i * 32, cs = (sc ^ row) & 7;
    gload_lds16(A + (size_t)(m0 + row) * lda + cs * 8, at[0] + i * 2048 + w * 512);
    gload_lds16(B + (size_t)(n0 + row) * ldb + cs * 8, bt[0] + i * 2048 + w * 512);
  }
  __syncthreads();

  for (int kt = 0; kt < nk; ++kt) {
    const int cur = kt & 1;
    if (kt + 1 < nk) {
      #pragma unroll
      for (int i = 0; i < 4; ++i) {
        int row = srow + i * 32, cs = (sc ^ row) & 7;
        int kcol = (kt + 1) * 64 + cs * 8;
        gload_lds16(A + (size_t)(m0 + row) * lda + kcol, at[cur ^ 1] + i * 2048 + w * 512);
        gload_lds16(B + (size_t)(n0 + row) * ldb + kcol, bt[cur ^ 1] + i * 2048 + w * 512);
      }
    }
    #pragma unroll
    for (int ks = 0; ks < 2; ++ks) {
      bf16x8 af[4], bff[4];
      #pragma unroll
      for (int m = 0; m < 4; ++m) {
        int row = (w >> 1) * 64 + m * 16 + r;
        int cs = ((ks * 4 + kg) ^ row) & 7;
        af[m] = *(const bf16x8*)(at[cur] + row * 64 + cs * 8);
      }
      #pragma unroll
      for (int n = 0; n < 4; ++n) {
        int row = (w & 1) * 64 + n * 16 + r;
        int cs = ((ks * 4 + kg) ^ row) & 7;
        bff[n] = *(const bf16x8*)(bt[cur] + row * 64 + cs * 8);
      }
      #pragma unroll
      for (int m = 0; m < 4; ++m)
        #pragma unroll
        for (int n = 0; n < 4; ++n)
          acc[m][n] = __builtin_amdgcn_mfma_f32_16x16x32_bf16(af[m], bff[n], acc[m][n], 0, 0, 0);
    }
    __syncthreads();
  }

  #pragma unroll
  for (int m = 0; m < 4; ++m) {
    #pragma unroll
    for (int n = 0; n < 4; ++n) {
      const int gcol = n0 + (w & 1) * 64 + n * 16 + r;
      #pragma unroll
      for (int reg = 0; reg < 4; ++reg) {
        const int grow = m0 + (w >> 1) * 64 + m * 16 + kg * 4 + reg;
        float v = acc[m][n][reg];
        if (EPI == 0) v = (v + bias[gcol]) * scale;
        if (EPI == 1) v = v + bias[grow];
        if (EPI == 2) { v += bias[gcol]; v = 0.5f * v * (1.f + erff(v * 0.70710678118654752f)); }
        if (EPI == 4) v = v * scale;
        if (EPI == 5) v = v / bias[grow];
        if (EPI == 3) {
          v += bias[gcol];
          float a = alpha[gcol];
          v = (v >= 0.f) ? v : a * v;
          ((float*)C)[(size_t)grow * ldc + coff + gcol] = v;
        } else {
          ((u16*)C)[(size_t)grow * ldc + coff + gcol] = f2bf(v);
        }
      }
    }
  }
}

// ---------------- fused exp + row-sum: P = exp(D*S) in-place, ls[row] = sum P ----
// One wave owns one full row (no atomics, deterministic). Grid 2048 x 256.
__global__ __launch_bounds__(256) void exp_kernel(
    u16* __restrict__ SP, const float* __restrict__ Dm, float* __restrict__ ls)
{
  const int w = threadIdx.x >> 6, lane = threadIdx.x & 63;
  const int row = blockIdx.x * 4 + w;
  u16* sp = SP + (size_t)row * 8192;
  const float* dp = Dm + (size_t)row * 8192;
  float acc = 0.f;
  #pragma unroll 2
  for (int it = 0; it < 16; ++it) {
    const int c = it * 512 + lane * 8;
    const u32x4 sv = *(const u32x4*)(sp + c);
    const u32x4 d0 = __builtin_nontemporal_load((const u32x4*)(dp + c));
    const u32x4 d1 = __builtin_nontemporal_load((const u32x4*)(dp + c + 4));
    u32x4 ow;
    #pragma unroll
    for (int kp = 0; kp < 4; ++kp) {
      union { unsigned u; float f; } s0, s1, e0, e1;
      s0.u = (sv[kp] & 0xffffu) << 16;
      s1.u = sv[kp] & 0xffff0000u;
      e0.u = (kp < 2) ? d0[kp * 2] : d1[(kp - 2) * 2];
      e1.u = (kp < 2) ? d0[kp * 2 + 1] : d1[(kp - 2) * 2 + 1];
      const float p0 = __expf(s0.f * e0.f);
      const float p1 = __expf(s1.f * e1.f);
      acc += p0 + p1;
      ow[kp] = (unsigned)f2bf(p0) | ((unsigned)f2bf(p1) << 16);
    }
    *(u32x4*)(sp + c) = ow;
  }
  #pragma unroll
  for (int m = 1; m < 64; m <<= 1) acc += __shfl_xor(acc, m);
  if (lane == 0) ls[row] = acc;
}

// ---------------- GroupNorm ----------------
__global__ void gn_stats_kernel(const float* __restrict__ x, float* __restrict__ part) {
  const int g = blockIdx.x >> 4, ch = blockIdx.x & 15;
  const int t = threadIdx.x;
  float s = 0.f, ss = 0.f;
  const int cl = (t & 7) * 4;
  const int r0 = ch * 512 + (t >> 3);
  for (int i = 0; i < 16; ++i) {
    const float4 v = *(const float4*)(x + (size_t)(r0 + i * 32) * 512 + g * 32 + cl);
    s += v.x + v.y + v.z + v.w;
    ss += v.x * v.x + v.y * v.y + v.z * v.z + v.w * v.w;
  }
  #pragma unroll
  for (int m = 1; m < 64; m <<= 1) { s += __shfl_xor(s, m); ss += __shfl_xor(ss, m); }
  __shared__ float red[8];
  const int w = t >> 6, lane = t & 63;
  if (lane == 0) { red[w * 2] = s; red[w * 2 + 1] = ss; }
  __syncthreads();
  if (t == 0) {
    part[blockIdx.x * 2]     = red[0] + red[2] + red[4] + red[6];
    part[blockIdx.x * 2 + 1] = red[1] + red[3] + red[5] + red[7];
  }
}

__global__ void gn_finalize_kernel(const float* __restrict__ part, float* __restrict__ mv) {
  const int g = threadIdx.x;
  if (g < 16) {
    float s = 0.f, ss = 0.f;
    for (int ch = 0; ch < 16; ++ch) {
      s  += part[(g * 16 + ch) * 2];
      ss += part[(g * 16 + ch) * 2 + 1];
    }
    const float mean = s * (1.f / 262144.f);
    const float var = ss * (1.f / 262144.f) - mean * mean;
    mv[g * 2] = mean;
    mv[g * 2 + 1] = rsqrtf(var + 1e-5f);
  }
}

__global__ void gn_norm_kernel(const float* __restrict__ x, const float* __restrict__ mv,
                               const float* __restrict__ gamma, const float* __restrict__ beta,
                               float* __restrict__ out) {
  const int idx = (blockIdx.x * 256 + threadIdx.x) * 4;
  const int c = idx & 511, g = c >> 5;
  const float mean = mv[g * 2], rs = mv[g * 2 + 1];
  float4 v = *(const float4*)(x + idx);
  const float4 gm = *(const float4*)(gamma + c);
  const float4 bt = *(const float4*)(beta + c);
  v.x = (v.x - mean) * rs * gm.x + bt.x;
  v.y = (v.y - mean) * rs * gm.y + bt.y;
  v.z = (v.z - mean) * rs * gm.z + bt.z;
  v.w = (v.w - mean) * rs * gm.w + bt.w;
  *(float4*)(out + idx) = v;
}

// ---------------- launch ----------------
// ws lifetime plan (<= ~173.6 MB):
//  [0,128M)   S/P bf16 8192x8192 (written step3).  Sub-lifetimes before/after:
//             hb   [0,16M)  steps1-2 ;  xcat [0,32M) steps6-7 ; xf [32M,48M) steps7-8
//  [128,144M) hpb   (live to step6)
//  [144,152M) Qb (steps2-3) then hrb (steps5-6)
//  [152,160M) Kb (steps2-3)
//  [160,168M) VTb (steps2-5)
//  [168M..)   weights (5.5MB), lsum, gp, mv
extern "C" void kernel_launch(void* const* d_in, const int* in_sizes, int n_in,
                              void* d_out, int out_size, void* d_ws, size_t ws_size,
                              hipStream_t stream) {
  (void)in_sizes; (void)n_in; (void)out_size; (void)ws_size;
  const float* h     = (const float*)d_in[0];
  const float* Dm    = (const float*)d_in[1];
  const float* hp    = (const float*)d_in[2];
  const float* Wq    = (const float*)d_in[3];
  const float* bq    = (const float*)d_in[4];
  const float* Wk    = (const float*)d_in[5];
  const float* bk    = (const float*)d_in[6];
  const float* Wv    = (const float*)d_in[7];
  const float* bv    = (const float*)d_in[8];
  const float* Wr    = (const float*)d_in[9];
  const float* br    = (const float*)d_in[10];
  const float* Wc    = (const float*)d_in[11];
  const float* bc    = (const float*)d_in[12];
  const float* Wp    = (const float*)d_in[13];
  const float* bp    = (const float*)d_in[14];
  const float* alpha = (const float*)d_in[15];
  const float* gamma = (const float*)d_in[16];
  const float* beta  = (const float*)d_in[17];

  char* ws = (char*)d_ws;
  const size_t MB = 1ull << 20;
  u16*   S    = (u16*)(ws);                 // 128 MB, S then P in-place
  u16*   hb   = (u16*)(ws);                 // 16 MB transient
  u16*   xcat = (u16*)(ws);                 // 32 MB transient
  float* xf   = (float*)(ws + 32 * MB);     // 16 MB
  u16*   hpb  = (u16*)(ws + 128 * MB);
  u16*   Qb   = (u16*)(ws + 144 * MB);
  u16*   hrb  = (u16*)(ws + 144 * MB);      // reuses Qb slot after S-GEMM
  u16*   Kb   = (u16*)(ws + 152 * MB);
  u16*   VTb  = (u16*)(ws + 160 * MB);
  u16*   Wqb  = (u16*)(ws + 168 * MB);
  u16*   Wkb  = Wqb + 262144;
  u16*   Wvb  = Wkb + 262144;
  u16*   Wrb  = Wvb + 262144;
  u16*   Wcb  = Wrb + 524288;
  u16*   Wpb  = Wcb + 524288;
  float* lsum = (float*)(ws + 168 * MB + 5767168);
  float* gp   = lsum + 8192;
  float* mv   = gp + 512;

  // 1. casts
  cast_kernel<<<4096, 256, 0, stream>>>(h, hb, 4194304);
  cast_kernel<<<4096, 256, 0, stream>>>(hp, hpb, 4194304);
  cast_kernel<<<256, 256, 0, stream>>>(Wq, Wqb, 262144);
  cast_kernel<<<256, 256, 0, stream>>>(Wk, Wkb, 262144);
  cast_kernel<<<256, 256, 0, stream>>>(Wv, Wvb, 262144);
  cast_kernel<<<512, 256, 0, stream>>>(Wr, Wrb, 524288);
  cast_kernel<<<512, 256, 0, stream>>>(Wc, Wcb, 524288);
  cast_kernel<<<1024, 256, 0, stream>>>(Wp, Wpb, 1048576);

  // 2. Q = (h Wq^T + bq)/sqrt(512) ; K = h Wk^T + bk ; V^T = Wv h^T + bv (row bias)
  gemm_nt<0><<<256, 256, 0, stream>>>(hb, 512, Wqb, 512, Qb, 512, 0, bq, nullptr, 4, 512, 0.044194173824159216f, 0);
  gemm_nt<0><<<256, 256, 0, stream>>>(hb, 512, Wkb, 512, Kb, 512, 0, bk, nullptr, 4, 512, 1.0f, 0);
  gemm_nt<1><<<256, 256, 0, stream>>>(Wvb, 512, hb, 512, VTb, 8192, 0, bv, nullptr, 64, 512, 1.0f, 0);

  // 3. S = Q K^T  (scale already folded into Q), bf16
  gemm_nt<4><<<4096, 256, 0, stream>>>(Qb, 512, Kb, 512, S, 8192, 0, nullptr, nullptr, 64, 512, 1.0f, 2);

  // 4. P = exp(D * S) in-place + per-row sums
  exp_kernel<<<2048, 256, 0, stream>>>(S, Dm, lsum);

  // 5. h_ret_raw = P V / lsum[row], bf16  (B = V^T so B^T = V)
  gemm_nt<5><<<256, 256, 0, stream>>>(S, 8192, VTb, 8192, hrb, 512, 0, lsum, nullptr, 4, 8192, 1.0f, 1);

  // 6. xcat[:, :1024] = gelu(h_ret Wr^T + br) ; xcat[:, 1024:] = h' Wc^T + bc
  gemm_nt<2><<<512, 256, 0, stream>>>(hrb, 512, Wrb, 512, xcat, 2048, 0, br, nullptr, 8, 512, 1.0f, 0);
  gemm_nt<0><<<512, 256, 0, stream>>>(hpb, 512, Wcb, 512, xcat, 2048, 1024, bc, nullptr, 8, 512, 1.0f, 0);

  // 7. x = prelu(xcat Wp^T + bp) (f32)
  gemm_nt<3><<<256, 256, 0, stream>>>(xcat, 2048, Wpb, 2048, xf, 512, 0, bp, alpha, 4, 2048, 1.0f, 0);

  // 8. GroupNorm
  gn_stats_kernel<<<256, 256, 0, stream>>>(xf, gp);
  gn_finalize_kernel<<<1, 64, 0, stream>>>(gp, mv);
  gn_norm_kernel<<<4096, 256, 0, stream>>>(xf, mv, gamma, beta, (float*)d_out);
}

// Round 6
// 439.275 us; speedup vs baseline: 1.5310x; 1.0536x over previous
//
#include <hip/hip_runtime.h>
#include <stdint.h>
#include <math.h>

typedef float f32x4 __attribute__((ext_vector_type(4)));
typedef __bf16 bf16x8 __attribute__((ext_vector_type(8)));
typedef unsigned int u32x4 __attribute__((ext_vector_type(4)));
typedef unsigned short u16;

#define DEVINL static __device__ __forceinline__

DEVINL u16 f2bf(float f) {
  union { float f; unsigned u; } x; x.f = f;
  unsigned r = x.u + 0x7fffu + ((x.u >> 16) & 1u);
  return (u16)(r >> 16);
}

DEVINL void gload_lds16(const void* g, void* l) {
  __builtin_amdgcn_global_load_lds(
      (__attribute__((address_space(1))) void*)(g),
      (__attribute__((address_space(3))) void*)(l), 16, 0, 0);
}

// ---------------- cast f32 -> bf16 ----------------
__global__ void cast_kernel(const float* __restrict__ src, u16* __restrict__ dst, int n) {
  int i = (blockIdx.x * 256 + threadIdx.x) * 4;
  if (i >= n) return;
  float4 v = *(const float4*)(src + i);
  u16 o[4] = { f2bf(v.x), f2bf(v.y), f2bf(v.z), f2bf(v.w) };
  *(uint64_t*)(dst + i) = *(uint64_t*)o;
}

// ---------------- NT GEMM: C[M,N] = A[M,K] @ B[N,K]^T, 128x128 tile ----------------
// EPI: 0 = (acc+bias[col])*scale -> bf16 ; 1 = acc+bias[row] -> bf16 (V^T)
//      2 = gelu(acc+bias[col]) -> bf16   ; 3 = prelu(acc+bias[col], alpha[col]) -> f32
//      5 = acc / bias[row] -> bf16 (PV normalize)
//      6 = fused retention softmax-numerator: P = exp(Dmat*acc) -> bf16,
//          psum[row*128 + bn*2 + (w&1)] = partial row sums (deterministic)
// map: 0 = linear (bm=bid/N128); 1 = PV XCD-grouped (grid 256, N128=4);
//      2 = S-GEMM XCD-chunked (grid 4096, N128=64)
template<int EPI>
__global__ __launch_bounds__(256, 2) void gemm_nt(
    const u16* __restrict__ A, int lda, const u16* __restrict__ B, int ldb,
    void* __restrict__ C, int ldc, int coff,
    const float* __restrict__ bias, const float* __restrict__ alpha,
    int N128, int K, float scale, int map,
    const float* __restrict__ Dmat, float* __restrict__ psum)
{
  __shared__ __align__(16) u16 at[2][128 * 64];
  __shared__ __align__(16) u16 bt[2][128 * 64];
  const int tid = threadIdx.x;
  const int w = tid >> 6, lane = tid & 63, r = lane & 15, kg = lane >> 4;
  int bm, bn;
  if (map == 1)      { const int x = blockIdx.x & 7, i = blockIdx.x >> 3; bm = x * 8 + (i >> 2); bn = i & 3; }
  else if (map == 2) { const int x = blockIdx.x & 7, i = blockIdx.x >> 3; bm = x * 8 + (i >> 6); bn = i & 63; }
  else               { bm = blockIdx.x / N128; bn = blockIdx.x % N128; }
  const int m0 = bm * 128, n0 = bn * 128;

  f32x4 acc[4][4];
  #pragma unroll
  for (int m = 0; m < 4; ++m)
    #pragma unroll
    for (int n = 0; n < 4; ++n) acc[m][n] = f32x4{0.f, 0.f, 0.f, 0.f};

  const int srow = tid >> 3, sc = tid & 7;
  const int nk = K >> 6;

  #pragma unroll
  for (int i = 0; i < 4; ++i) {
    int row = srow + i * 32, cs = (sc ^ row) & 7;
    gload_lds16(A + (size_t)(m0 + row) * lda + cs * 8, at[0] + i * 2048 + w * 512);
    gload_lds16(B + (size_t)(n0 + row) * ldb + cs * 8, bt[0] + i * 2048 + w * 512);
  }
  __syncthreads();

  for (int kt = 0; kt < nk; ++kt) {
    const int cur = kt & 1;
    if (kt + 1 < nk) {
      #pragma unroll
      for (int i = 0; i < 4; ++i) {
        int row = srow + i * 32, cs = (sc ^ row) & 7;
        int kcol = (kt + 1) * 64 + cs * 8;
        gload_lds16(A + (size_t)(m0 + row) * lda + kcol, at[cur ^ 1] + i * 2048 + w * 512);
        gload_lds16(B + (size_t)(n0 + row) * ldb + kcol, bt[cur ^ 1] + i * 2048 + w * 512);
      }
    }
    #pragma unroll
    for (int ks = 0; ks < 2; ++ks) {
      bf16x8 af[4], bff[4];
      #pragma unroll
      for (int m = 0; m < 4; ++m) {
        int row = (w >> 1) * 64 + m * 16 + r;
        int cs = ((ks * 4 + kg) ^ row) & 7;
        af[m] = *(const bf16x8*)(at[cur] + row * 64 + cs * 8);
      }
      #pragma unroll
      for (int n = 0; n < 4; ++n) {
        int row = (w & 1) * 64 + n * 16 + r;
        int cs = ((ks * 4 + kg) ^ row) & 7;
        bff[n] = *(const bf16x8*)(bt[cur] + row * 64 + cs * 8);
      }
      #pragma unroll
      for (int m = 0; m < 4; ++m)
        #pragma unroll
        for (int n = 0; n < 4; ++n)
          acc[m][n] = __builtin_amdgcn_mfma_f32_16x16x32_bf16(af[m], bff[n], acc[m][n], 0, 0, 0);
    }
    __syncthreads();
  }

  if (EPI == 6) {
    // fused exp(D*S) epilogue + deterministic partial row sums
    #pragma unroll
    for (int m = 0; m < 4; ++m) {
      float rs[4] = {0.f, 0.f, 0.f, 0.f};
      #pragma unroll
      for (int n = 0; n < 4; ++n) {
        const int gcol = n0 + (w & 1) * 64 + n * 16 + r;
        #pragma unroll
        for (int reg = 0; reg < 4; ++reg) {
          const int grow = m0 + (w >> 1) * 64 + m * 16 + kg * 4 + reg;
          const float dv = __builtin_nontemporal_load(Dmat + (size_t)grow * 8192 + gcol);
          const float p = __expf(acc[m][n][reg] * dv);
          rs[reg] += p;
          ((u16*)C)[(size_t)grow * ldc + gcol] = f2bf(p);
        }
      }
      #pragma unroll
      for (int reg = 0; reg < 4; ++reg) {
        float v = rs[reg];
        v += __shfl_xor(v, 1); v += __shfl_xor(v, 2);
        v += __shfl_xor(v, 4); v += __shfl_xor(v, 8);
        if (r == 0) {
          const int grow = m0 + (w >> 1) * 64 + m * 16 + kg * 4 + reg;
          psum[(size_t)grow * 128 + bn * 2 + (w & 1)] = v;
        }
      }
    }
    return;
  }

  #pragma unroll
  for (int m = 0; m < 4; ++m) {
    #pragma unroll
    for (int n = 0; n < 4; ++n) {
      const int gcol = n0 + (w & 1) * 64 + n * 16 + r;
      #pragma unroll
      for (int reg = 0; reg < 4; ++reg) {
        const int grow = m0 + (w >> 1) * 64 + m * 16 + kg * 4 + reg;
        float v = acc[m][n][reg];
        if (EPI == 0) v = (v + bias[gcol]) * scale;
        if (EPI == 1) v = v + bias[grow];
        if (EPI == 2) { v += bias[gcol]; v = 0.5f * v * (1.f + erff(v * 0.70710678118654752f)); }
        if (EPI == 5) v = v / bias[grow];
        if (EPI == 3) {
          v += bias[gcol];
          float a = alpha[gcol];
          v = (v >= 0.f) ? v : a * v;
          ((float*)C)[(size_t)grow * ldc + coff + gcol] = v;
        } else {
          ((u16*)C)[(size_t)grow * ldc + coff + gcol] = f2bf(v);
        }
      }
    }
  }
}

// ---------------- reduce psum[8192][128] -> lsum[8192] ----------------
__global__ __launch_bounds__(256) void rowsum_kernel(const float* __restrict__ psum,
                                                     float* __restrict__ ls) {
  const int row = blockIdx.x * 4 + (threadIdx.x >> 6);
  const int lane = threadIdx.x & 63;
  const float2 v = *(const float2*)(psum + (size_t)row * 128 + lane * 2);
  float s = v.x + v.y;
  #pragma unroll
  for (int m = 1; m < 64; m <<= 1) s += __shfl_xor(s, m);
  if (lane == 0) ls[row] = s;
}

// ---------------- GroupNorm ----------------
__global__ void gn_stats_kernel(const float* __restrict__ x, float* __restrict__ part) {
  const int g = blockIdx.x >> 4, ch = blockIdx.x & 15;
  const int t = threadIdx.x;
  float s = 0.f, ss = 0.f;
  const int cl = (t & 7) * 4;
  const int r0 = ch * 512 + (t >> 3);
  for (int i = 0; i < 16; ++i) {
    const float4 v = *(const float4*)(x + (size_t)(r0 + i * 32) * 512 + g * 32 + cl);
    s += v.x + v.y + v.z + v.w;
    ss += v.x * v.x + v.y * v.y + v.z * v.z + v.w * v.w;
  }
  #pragma unroll
  for (int m = 1; m < 64; m <<= 1) { s += __shfl_xor(s, m); ss += __shfl_xor(ss, m); }
  __shared__ float red[8];
  const int w = t >> 6, lane = t & 63;
  if (lane == 0) { red[w * 2] = s; red[w * 2 + 1] = ss; }
  __syncthreads();
  if (t == 0) {
    part[blockIdx.x * 2]     = red[0] + red[2] + red[4] + red[6];
    part[blockIdx.x * 2 + 1] = red[1] + red[3] + red[5] + red[7];
  }
}

__global__ void gn_finalize_kernel(const float* __restrict__ part, float* __restrict__ mv) {
  const int g = threadIdx.x;
  if (g < 16) {
    float s = 0.f, ss = 0.f;
    for (int ch = 0; ch < 16; ++ch) {
      s  += part[(g * 16 + ch) * 2];
      ss += part[(g * 16 + ch) * 2 + 1];
    }
    const float mean = s * (1.f / 262144.f);
    const float var = ss * (1.f / 262144.f) - mean * mean;
    mv[g * 2] = mean;
    mv[g * 2 + 1] = rsqrtf(var + 1e-5f);
  }
}

__global__ void gn_norm_kernel(const float* __restrict__ x, const float* __restrict__ mv,
                               const float* __restrict__ gamma, const float* __restrict__ beta,
                               float* __restrict__ out) {
  const int idx = (blockIdx.x * 256 + threadIdx.x) * 4;
  const int c = idx & 511, g = c >> 5;
  const float mean = mv[g * 2], rs = mv[g * 2 + 1];
  float4 v = *(const float4*)(x + idx);
  const float4 gm = *(const float4*)(gamma + c);
  const float4 bt = *(const float4*)(beta + c);
  v.x = (v.x - mean) * rs * gm.x + bt.x;
  v.y = (v.y - mean) * rs * gm.y + bt.y;
  v.z = (v.z - mean) * rs * gm.z + bt.z;
  v.w = (v.w - mean) * rs * gm.w + bt.w;
  *(float4*)(out + idx) = v;
}

// ---------------- launch ----------------
// ws plan (ws_size ~1GB per R5 fill evidence; keep < 200MB):
//  [0,128M)   P bf16 8192x8192 (written by fused S-GEMM step3)
//             hb   [0,16M)  steps1-2 ;  xcat [0,32M) steps5-6 ; xf [32M,48M) steps6-7
//  [128,144M) hpb   (live to step5)
//  [144,152M) Qb (steps2-3) then hrb (steps4-5)
//  [152,160M) Kb (steps2-3)
//  [160,168M) VTb (steps2-4)
//  [168M..)   weights (5.5MB), lsum, gp, mv
//  [176,180M) psum f32 [8192][128]
extern "C" void kernel_launch(void* const* d_in, const int* in_sizes, int n_in,
                              void* d_out, int out_size, void* d_ws, size_t ws_size,
                              hipStream_t stream) {
  (void)in_sizes; (void)n_in; (void)out_size; (void)ws_size;
  const float* h     = (const float*)d_in[0];
  const float* Dm    = (const float*)d_in[1];
  const float* hp    = (const float*)d_in[2];
  const float* Wq    = (const float*)d_in[3];
  const float* bq    = (const float*)d_in[4];
  const float* Wk    = (const float*)d_in[5];
  const float* bk    = (const float*)d_in[6];
  const float* Wv    = (const float*)d_in[7];
  const float* bv    = (const float*)d_in[8];
  const float* Wr    = (const float*)d_in[9];
  const float* br    = (const float*)d_in[10];
  const float* Wc    = (const float*)d_in[11];
  const float* bc    = (const float*)d_in[12];
  const float* Wp    = (const float*)d_in[13];
  const float* bp    = (const float*)d_in[14];
  const float* alpha = (const float*)d_in[15];
  const float* gamma = (const float*)d_in[16];
  const float* beta  = (const float*)d_in[17];

  char* ws = (char*)d_ws;
  const size_t MB = 1ull << 20;
  u16*   P    = (u16*)(ws);                 // 128 MB
  u16*   hb   = (u16*)(ws);                 // 16 MB transient
  u16*   xcat = (u16*)(ws);                 // 32 MB transient
  float* xf   = (float*)(ws + 32 * MB);     // 16 MB
  u16*   hpb  = (u16*)(ws + 128 * MB);
  u16*   Qb   = (u16*)(ws + 144 * MB);
  u16*   hrb  = (u16*)(ws + 144 * MB);      // reuses Qb slot after S-GEMM
  u16*   Kb   = (u16*)(ws + 152 * MB);
  u16*   VTb  = (u16*)(ws + 160 * MB);
  u16*   Wqb  = (u16*)(ws + 168 * MB);
  u16*   Wkb  = Wqb + 262144;
  u16*   Wvb  = Wkb + 262144;
  u16*   Wrb  = Wvb + 262144;
  u16*   Wcb  = Wrb + 524288;
  u16*   Wpb  = Wcb + 524288;
  float* lsum = (float*)(ws + 168 * MB + 5767168);
  float* gp   = lsum + 8192;
  float* mv   = gp + 512;
  float* psum = (float*)(ws + 176 * MB);    // 4 MB

  // 1. casts
  cast_kernel<<<4096, 256, 0, stream>>>(h, hb, 4194304);
  cast_kernel<<<4096, 256, 0, stream>>>(hp, hpb, 4194304);
  cast_kernel<<<256, 256, 0, stream>>>(Wq, Wqb, 262144);
  cast_kernel<<<256, 256, 0, stream>>>(Wk, Wkb, 262144);
  cast_kernel<<<256, 256, 0, stream>>>(Wv, Wvb, 262144);
  cast_kernel<<<512, 256, 0, stream>>>(Wr, Wrb, 524288);
  cast_kernel<<<512, 256, 0, stream>>>(Wc, Wcb, 524288);
  cast_kernel<<<1024, 256, 0, stream>>>(Wp, Wpb, 1048576);

  // 2. Q = (h Wq^T + bq)/sqrt(512) ; K = h Wk^T + bk ; V^T = Wv h^T + bv (row bias)
  gemm_nt<0><<<256, 256, 0, stream>>>(hb, 512, Wqb, 512, Qb, 512, 0, bq, nullptr, 4, 512, 0.044194173824159216f, 0, nullptr, nullptr);
  gemm_nt<0><<<256, 256, 0, stream>>>(hb, 512, Wkb, 512, Kb, 512, 0, bk, nullptr, 4, 512, 1.0f, 0, nullptr, nullptr);
  gemm_nt<1><<<256, 256, 0, stream>>>(Wvb, 512, hb, 512, VTb, 8192, 0, bv, nullptr, 64, 512, 1.0f, 0, nullptr, nullptr);

  // 3. P = exp(D * (Q K^T)) fused; psum partials (scale folded into Q)
  gemm_nt<6><<<4096, 256, 0, stream>>>(Qb, 512, Kb, 512, P, 8192, 0, nullptr, nullptr, 64, 512, 1.0f, 2, Dm, psum);
  rowsum_kernel<<<2048, 256, 0, stream>>>(psum, lsum);

  // 4. h_ret_raw = P V / lsum[row], bf16  (B = V^T so B^T = V)
  gemm_nt<5><<<256, 256, 0, stream>>>(P, 8192, VTb, 8192, hrb, 512, 0, lsum, nullptr, 4, 8192, 1.0f, 1, nullptr, nullptr);

  // 5. xcat[:, :1024] = gelu(h_ret Wr^T + br) ; xcat[:, 1024:] = h' Wc^T + bc
  gemm_nt<2><<<512, 256, 0, stream>>>(hrb, 512, Wrb, 512, xcat, 2048, 0, br, nullptr, 8, 512, 1.0f, 0, nullptr, nullptr);
  gemm_nt<0><<<512, 256, 0, stream>>>(hpb, 512, Wcb, 512, xcat, 2048, 1024, bc, nullptr, 8, 512, 1.0f, 0, nullptr, nullptr);

  // 6. x = prelu(xcat Wp^T + bp) (f32)
  gemm_nt<3><<<256, 256, 0, stream>>>(xcat, 2048, Wpb, 2048, xf, 512, 0, bp, alpha, 4, 2048, 1.0f, 0, nullptr, nullptr);

  // 7. GroupNorm
  gn_stats_kernel<<<256, 256, 0, stream>>>(xf, gp);
  gn_finalize_kernel<<<1, 64, 0, stream>>>(gp, mv);
  gn_norm_kernel<<<4096, 256, 0, stream>>>(xf, mv, gamma, beta, (float*)d_out);
}